// Round 10
// baseline (201.335 us; speedup 1.0000x reference)
//
#include <hip/hip_runtime.h>
#include <hip/hip_fp16.h>

#define NN 10000
#define NE 320000
#define D 256
#define BH 128         // histogram blocks
#define EPB (NE / BH)  // 2500 edges per block (exact)
#define CSZ 16         // edges per phase-1 chunk
#define MAXCH 30000    // >= NE/CSZ + NN (worst-case chunk count)

// ---------------- DPP cross-lane helpers (VALU pipe) -------------------------

template<int CTRL>
__device__ __forceinline__ float dpp_add(float x) {
    int y = __builtin_amdgcn_update_dpp(0, __float_as_int(x), CTRL, 0xF, 0xF, true);
    return x + __int_as_float(y);
}

// full 64-lane sum, result uniform via readlane 63
__device__ __forceinline__ float wave_red_sum(float x) {
    x = dpp_add<0x111>(x);   // row_shr:1
    x = dpp_add<0x112>(x);   // row_shr:2
    x = dpp_add<0x114>(x);   // row_shr:4
    x = dpp_add<0x118>(x);   // row_shr:8
    x = dpp_add<0x142>(x);   // row_bcast15
    x = dpp_add<0x143>(x);   // row_bcast31
    return __int_as_float(__builtin_amdgcn_readlane(__float_as_int(x), 63));
}

__device__ __forceinline__ float rl_f(float x, int t) {
    return __int_as_float(__builtin_amdgcn_readlane(__float_as_int(x), t));
}

union H2U { __half2 h; unsigned u; };

__device__ __forceinline__ float4 unpack4(uint2 r) {
    H2U a, b; a.u = r.x; b.u = r.y;
    float2 f01 = __half22float2(a.h);
    float2 f23 = __half22float2(b.h);
    return make_float4(f01.x, f01.y, f23.x, f23.y);
}

__device__ __forceinline__ uint2 pack4(float4 v) {
    H2U a, b;
    a.h = __floats2half2_rn(v.x, v.y);
    b.h = __floats2half2_rn(v.z, v.w);
    return make_uint2(a.u, b.u);
}

// ---------------- CSR build: atomic-free (LDS histograms) --------------------

__global__ void hist_rank_kernel(const int* __restrict__ dst,
                                 int* __restrict__ blockhist, int* __restrict__ rank) {
    __shared__ int lh[NN];                       // 40 KB
    for (int i = threadIdx.x; i < NN; i += 256) lh[i] = 0;
    __syncthreads();
    int e0 = blockIdx.x * EPB, e1 = e0 + EPB;
    for (int e = e0 + threadIdx.x; e < e1; e += 256)
        rank[e] = atomicAdd(&lh[dst[e]], 1);     // LDS atomic
    __syncthreads();
    int* bh = blockhist + blockIdx.x * NN;
    for (int i = threadIdx.x; i < NN; i += 256) bh[i] = lh[i];
}

__global__ void colscan_kernel(int* __restrict__ blockhist, int* __restrict__ cnt, int n) {
    int d = blockIdx.x * blockDim.x + threadIdx.x;
    if (d >= n) return;
    int run = 0;
    for (int b = 0; b < BH; ++b) {
        int v = blockhist[b * NN + d];           // coalesced across d
        blockhist[b * NN + d] = run;
        run += v;
    }
    cnt[d] = run;
}

// generic single-block exclusive scan: cnt[0..n) -> ofs[0..n]
__global__ void scan_kernel(const int* __restrict__ cnt, int* __restrict__ ofs, int n) {
    __shared__ int part[256];
    int t = threadIdx.x;
    int chunk = (n + 255) / 256;
    int b = t * chunk;
    int e = b + chunk; if (e > n) e = n;
    int s = 0;
    for (int i = b; i < e; ++i) s += cnt[i];
    part[t] = s;
    __syncthreads();
    for (int off = 1; off < 256; off <<= 1) {
        int v = (t >= off) ? part[t - off] : 0;
        __syncthreads();
        part[t] += v;
        __syncthreads();
    }
    int acc = part[t] - s;
    for (int i = b; i < e; ++i) { ofs[i] = acc; acc += cnt[i]; }
    if (e == n && b < n) ofs[n] = acc;
}

__global__ void scatter2_kernel(const int* __restrict__ src, const int* __restrict__ dst,
                                const int* __restrict__ rank, const int* __restrict__ blockhist,
                                const int* __restrict__ rowptr, int* __restrict__ esrc, int nE) {
    int e = blockIdx.x * blockDim.x + threadIdx.x;
    if (e >= nE) return;
    int b = e / EPB;
    int d = dst[e];
    esrc[rowptr[d] + blockhist[b * NN + d] + rank[e]] = src[e];
}

// chunk table: nchunk[n] = ceil(deg/CSZ); then scan -> chunkofs; then fill ids
__global__ void nchunk_kernel(const int* __restrict__ rowptr, int* __restrict__ nchunk, int n) {
    int d = blockIdx.x * blockDim.x + threadIdx.x;
    if (d >= n) return;
    int deg = rowptr[d + 1] - rowptr[d];
    nchunk[d] = (deg + CSZ - 1) / CSZ;
}

__global__ void fillchunk_kernel(const int* __restrict__ chunkofs, int* __restrict__ chunk_node, int n) {
    int d = blockIdx.x * blockDim.x + threadIdx.x;
    if (d >= n) return;
    int b = chunkofs[d], e = chunkofs[d + 1];
    for (int j = b; j < e; ++j) chunk_node[j] = d;
}

// ---------------- layer-0: normalized fp16 mirror + norms --------------------

__global__ void norm_kernel(const float4* __restrict__ h, uint2* __restrict__ hn,
                            float* __restrict__ nrm, int n) {
    int wid  = (blockIdx.x * blockDim.x + threadIdx.x) >> 6;
    int lane = threadIdx.x & 63;
    if (wid >= n) return;
    float4 v = h[wid * 64 + lane];
    float tot = wave_red_sum(v.x * v.x + v.y * v.y + v.z * v.z + v.w * v.w);
    float rs = rsqrtf(tot + 1e-16f);
    hn[wid * 64 + lane] = pack4(make_float4(v.x * rs, v.y * rs, v.z * rs, v.w * rs));
    if (lane == 0) nrm[wid] = 1.0f / rs;
}

// ---------------- phase 1: one wave per EDGE CHUNK (<=16 edges) --------------
// Edge-balanced: every wave does <=16 edges regardless of node degree.
// Gathers normalized fp16 rows (512 B = 64 lanes x 8 B); dot = cos directly;
// aggregation weight = ex * ||h_src||. Writes 1 KB f32 partial + partial dsum.

__global__ __launch_bounds__(256, 8)
void phase1_kernel(const uint2* __restrict__ hnin, const float* __restrict__ nrmin,
                   const int* __restrict__ rowptr, const int* __restrict__ chunkofs,
                   const int* __restrict__ chunk_node, const int* __restrict__ esrc,
                   const float* __restrict__ betas, int layer,
                   float4* __restrict__ pacc, float* __restrict__ pdsum) {
    int w    = (blockIdx.x * blockDim.x + threadIdx.x) >> 6;
    int lane = threadIdx.x & 63;
    int tot  = chunkofs[NN];
    if (w >= tot) return;

    int node = chunk_node[w];
    int rb   = rowptr[node];
    int j    = w - chunkofs[node];
    int cbeg = rb + j * CSZ;
    int cend = rowptr[node + 1];
    if (cend > cbeg + CSZ) cend = cbeg + CSZ;
    int m = cend - cbeg;                         // 1..16

    float4 a = unpack4(hnin[node * 64 + lane]);  // dst row (normalized)
    float beta = betas[layer];

    int s_l = 0; float nm_l = 0.f;
    if (lane < m) { s_l = esrc[cbeg + lane]; nm_l = nrmin[s_l]; }

    float4 acc = make_float4(0.f, 0.f, 0.f, 0.f);
    float dsum = 0.f;

    int nf = m & ~3;                             // full groups of 4
    uint2 b0, b1, b2, b3;
    if (nf > 0) {
        b0 = hnin[__builtin_amdgcn_readlane(s_l, 0) * 64 + lane];
        b1 = hnin[__builtin_amdgcn_readlane(s_l, 1) * 64 + lane];
        b2 = hnin[__builtin_amdgcn_readlane(s_l, 2) * 64 + lane];
        b3 = hnin[__builtin_amdgcn_readlane(s_l, 3) * 64 + lane];
    }
    for (int g = 0; g < nf; g += 4) {
        float4 v0 = unpack4(b0);
        float4 v1 = unpack4(b1);
        float4 v2 = unpack4(b2);
        float4 v3 = unpack4(b3);
        float n0 = rl_f(nm_l, g),     n1 = rl_f(nm_l, g + 1);
        float n2 = rl_f(nm_l, g + 2), n3 = rl_f(nm_l, g + 3);
        int gn = g + 4;
        if (gn < nf) {                           // prefetch next group
            b0 = hnin[__builtin_amdgcn_readlane(s_l, gn)     * 64 + lane];
            b1 = hnin[__builtin_amdgcn_readlane(s_l, gn + 1) * 64 + lane];
            b2 = hnin[__builtin_amdgcn_readlane(s_l, gn + 2) * 64 + lane];
            b3 = hnin[__builtin_amdgcn_readlane(s_l, gn + 3) * 64 + lane];
        }
        float p0 = a.x * v0.x + a.y * v0.y + a.z * v0.z + a.w * v0.w;
        float p1 = a.x * v1.x + a.y * v1.y + a.z * v1.z + a.w * v1.w;
        float p2 = a.x * v2.x + a.y * v2.y + a.z * v2.z + a.w * v2.w;
        float p3 = a.x * v3.x + a.y * v3.y + a.z * v3.z + a.w * v3.w;
        p0 = wave_red_sum(p0); p1 = wave_red_sum(p1);
        p2 = wave_red_sum(p2); p3 = wave_red_sum(p3);
        float e0 = __expf(beta * p0);
        float e1 = __expf(beta * p1);
        float e2 = __expf(beta * p2);
        float e3 = __expf(beta * p3);
        dsum += (e0 + e1) + (e2 + e3);
        float w0 = e0 * n0, w1 = e1 * n1, w2 = e2 * n2, w3 = e3 * n3;
        acc.x += w0 * v0.x + w1 * v1.x + w2 * v2.x + w3 * v3.x;
        acc.y += w0 * v0.y + w1 * v1.y + w2 * v2.y + w3 * v3.y;
        acc.z += w0 * v0.z + w1 * v1.z + w2 * v2.z + w3 * v3.z;
        acc.w += w0 * v0.w + w1 * v1.w + w2 * v2.w + w3 * v3.w;
    }
    for (int t = nf; t < m; ++t) {
        float4 v0 = unpack4(hnin[__builtin_amdgcn_readlane(s_l, t) * 64 + lane]);
        float n0 = rl_f(nm_l, t);
        float p0 = a.x * v0.x + a.y * v0.y + a.z * v0.z + a.w * v0.w;
        p0 = wave_red_sum(p0);
        float e0 = __expf(beta * p0);
        dsum += e0;
        float w0 = e0 * n0;
        acc.x += w0 * v0.x; acc.y += w0 * v0.y;
        acc.z += w0 * v0.z; acc.w += w0 * v0.w;
    }

    pacc[w * 64 + lane] = acc;                   // 1 KB coalesced partial
    if (lane == 0) pdsum[w] = dsum;
}

// ---------------- phase 2: one wave per node — combine chunks ----------------

__global__ void phase2_kernel(const int* __restrict__ chunkofs,
                              const float4* __restrict__ pacc, const float* __restrict__ pdsum,
                              float4* __restrict__ outf, uint2* __restrict__ hnout,
                              float* __restrict__ nrmout, int lastLayer, int n) {
    int node = (blockIdx.x * blockDim.x + threadIdx.x) >> 6;
    int lane = threadIdx.x & 63;
    if (node >= n) return;
    int cb = chunkofs[node], ce = chunkofs[node + 1];

    float4 acc = make_float4(0.f, 0.f, 0.f, 0.f);
    float dsum = 0.f;
    for (int c = cb; c < ce; ++c) {
        float4 p = pacc[c * 64 + lane];          // coalesced
        acc.x += p.x; acc.y += p.y; acc.z += p.z; acc.w += p.w;
        dsum += pdsum[c];                        // uniform broadcast load
    }

    float r = 1.f / (dsum + 1e-16f);
    float4 w;
    w.x = fmaxf(acc.x * r, 0.f); w.y = fmaxf(acc.y * r, 0.f);
    w.z = fmaxf(acc.z * r, 0.f); w.w = fmaxf(acc.w * r, 0.f);

    if (lastLayer) {
        outf[node * 64 + lane] = w;
    } else {
        float ss = wave_red_sum(w.x * w.x + w.y * w.y + w.z * w.z + w.w * w.w);
        float rs = rsqrtf(ss + 1e-16f);
        hnout[node * 64 + lane] = pack4(make_float4(w.x * rs, w.y * rs, w.z * rs, w.w * rs));
        if (lane == 0) nrmout[node] = 1.0f / rs;
    }
}

// ---------------- launch -----------------------------------------------------

extern "C" void kernel_launch(void* const* d_in, const int* in_sizes, int n_in,
                              void* d_out, int out_size, void* d_ws, size_t ws_size,
                              hipStream_t stream) {
    const float* feats = (const float*)d_in[0];
    const int*   src   = (const int*)d_in[1];
    const int*   dst   = (const int*)d_in[2];
    const float* betas = (const float*)d_in[3];
    float* out = (float*)d_out;

    float4* pacc      = (float4*)d_ws;                 // MAXCH*64 float4 (30.7 MB)
    uint2*  hn0       = (uint2*)(pacc + MAXCH * 64);   // NN*64 uint2 (5.12 MB)
    uint2*  hn1       = hn0 + NN * 64;                 // NN*64 uint2 (5.12 MB)
    float*  pdsum     = (float*)(hn1 + NN * 64);       // MAXCH floats
    float*  nrm0      = pdsum + MAXCH;                 // NN floats
    float*  nrm1      = nrm0 + NN;                     // NN floats
    int*    rowptr    = (int*)(nrm1 + NN);             // NN+1 ints
    int*    cnt       = rowptr + (NN + 1);             // NN ints
    int*    nchunk    = cnt + NN;                      // NN ints
    int*    chunkofs  = nchunk + NN;                   // NN+1 ints
    int*    chunk_node= chunkofs + (NN + 1);           // MAXCH ints
    int*    esrc      = chunk_node + MAXCH;            // NE ints
    int*    rank      = esrc + NE;                     // NE ints
    int*    blockhist = rank + NE;                     // BH*NN ints (5.12 MB)

    // CSR build — no global atomics, no memsets
    hist_rank_kernel<<<BH, 256, 0, stream>>>(dst, blockhist, rank);
    colscan_kernel<<<(NN + 255) / 256, 256, 0, stream>>>(blockhist, cnt, NN);
    scan_kernel<<<1, 256, 0, stream>>>(cnt, rowptr, NN);
    scatter2_kernel<<<(NE + 255) / 256, 256, 0, stream>>>(src, dst, rank, blockhist,
                                                          rowptr, esrc, NE);

    // chunk table (edge-balanced phase-1 work list)
    nchunk_kernel<<<(NN + 255) / 256, 256, 0, stream>>>(rowptr, nchunk, NN);
    scan_kernel<<<1, 256, 0, stream>>>(nchunk, chunkofs, NN);
    fillchunk_kernel<<<(NN + 255) / 256, 256, 0, stream>>>(chunkofs, chunk_node, NN);

    // layer-0: normalized fp16 mirror + norms
    norm_kernel<<<(NN * 64 + 255) / 256, 256, 0, stream>>>((const float4*)feats,
                                                           hn0, nrm0, NN);

    const int p1_blocks = MAXCH / 4;        // one wave per chunk (guard on device)
    const int p2_blocks = (NN + 3) / 4;     // one wave per node

    const uint2* hnin  = hn0;
    const float* nrmin = nrm0;
    for (int l = 0; l < 4; ++l) {
        uint2* hnout  = (l & 1) ? hn0 : hn1;
        float* nrmout = (l & 1) ? nrm0 : nrm1;
        phase1_kernel<<<p1_blocks, 256, 0, stream>>>(hnin, nrmin, rowptr, chunkofs,
                                                     chunk_node, esrc, betas, l,
                                                     pacc, pdsum);
        phase2_kernel<<<p2_blocks, 256, 0, stream>>>(chunkofs, pacc, pdsum,
                                                     (float4*)out, hnout, nrmout,
                                                     (l == 3) ? 1 : 0, NN);
        hnin  = hnout;
        nrmin = nrmout;
    }
}

// Round 11
// 166.841 us; speedup vs baseline: 1.2067x; 1.2067x over previous
//
#include <hip/hip_runtime.h>
#include <hip/hip_fp16.h>

#define NN 10000
#define NE 320000
#define D 256
#define BH 64          // histogram blocks
#define EPB (NE / BH)  // 5000 edges per block (exact)

// ---------------- DPP cross-lane helpers (VALU pipe) -------------------------

template<int CTRL>
__device__ __forceinline__ float dpp_add(float x) {
    int y = __builtin_amdgcn_update_dpp(0, __float_as_int(x), CTRL, 0xF, 0xF, true);
    return x + __int_as_float(y);
}

// 32-lane reduce: after this, lane31 = sum(lanes 0..31), lane63 = sum(lanes 32..63)
__device__ __forceinline__ float red32(float x) {
    x = dpp_add<0x111>(x);   // row_shr:1
    x = dpp_add<0x112>(x);   // row_shr:2
    x = dpp_add<0x114>(x);   // row_shr:4
    x = dpp_add<0x118>(x);   // row_shr:8
    x = dpp_add<0x142>(x);   // row_bcast15
    return x;
}

__device__ __forceinline__ float rl_f(float x, int t) {
    return __int_as_float(__builtin_amdgcn_readlane(__float_as_int(x), t));
}

union H2U { __half2 h; unsigned u; };

__device__ __forceinline__ void unpack8(uint4 r, float* v) {
    H2U a, b, c, d; a.u = r.x; b.u = r.y; c.u = r.z; d.u = r.w;
    float2 f;
    f = __half22float2(a.h); v[0] = f.x; v[1] = f.y;
    f = __half22float2(b.h); v[2] = f.x; v[3] = f.y;
    f = __half22float2(c.h); v[4] = f.x; v[5] = f.y;
    f = __half22float2(d.h); v[6] = f.x; v[7] = f.y;
}

// ---------------- CSR build: atomic-free (LDS histograms) --------------------

__global__ void hist_rank_kernel(const int* __restrict__ dst,
                                 int* __restrict__ blockhist, int* __restrict__ rank) {
    __shared__ int lh[NN];                       // 40 KB
    for (int i = threadIdx.x; i < NN; i += 256) lh[i] = 0;
    __syncthreads();
    int e0 = blockIdx.x * EPB, e1 = e0 + EPB;
    for (int e = e0 + threadIdx.x; e < e1; e += 256)
        rank[e] = atomicAdd(&lh[dst[e]], 1);     // LDS atomic
    __syncthreads();
    int* bh = blockhist + blockIdx.x * NN;
    for (int i = threadIdx.x; i < NN; i += 256) bh[i] = lh[i];
}

__global__ void colscan_kernel(int* __restrict__ blockhist, int* __restrict__ cnt, int n) {
    int d = blockIdx.x * blockDim.x + threadIdx.x;
    if (d >= n) return;
    int run = 0;
    for (int b = 0; b < BH; ++b) {
        int v = blockhist[b * NN + d];           // coalesced across d
        blockhist[b * NN + d] = run;
        run += v;
    }
    cnt[d] = run;
}

__global__ void scan_kernel(const int* __restrict__ cnt, int* __restrict__ rowptr, int n) {
    __shared__ int part[256];
    int t = threadIdx.x;
    int chunk = (n + 255) / 256;
    int b = t * chunk;
    int e = b + chunk; if (e > n) e = n;
    int s = 0;
    for (int i = b; i < e; ++i) s += cnt[i];
    part[t] = s;
    __syncthreads();
    for (int off = 1; off < 256; off <<= 1) {
        int v = (t >= off) ? part[t - off] : 0;
        __syncthreads();
        part[t] += v;
        __syncthreads();
    }
    int acc = part[t] - s;
    for (int i = b; i < e; ++i) { rowptr[i] = acc; acc += cnt[i]; }
    if (e == n && b < n) rowptr[n] = acc;
}

__global__ void scatter2_kernel(const int* __restrict__ src, const int* __restrict__ dst,
                                const int* __restrict__ rank, const int* __restrict__ blockhist,
                                const int* __restrict__ rowptr, int* __restrict__ esrc, int nE) {
    int e = blockIdx.x * blockDim.x + threadIdx.x;
    if (e >= nE) return;
    int b = e / EPB;
    int d = dst[e];
    esrc[rowptr[d] + blockhist[b * NN + d] + rank[e]] = src[e];
}

// ---------------- layer-0: normalized fp16 mirror + norms --------------------

__global__ void norm_kernel(const float4* __restrict__ h, uint2* __restrict__ hn,
                            float* __restrict__ nrm, int n) {
    int wid  = (blockIdx.x * blockDim.x + threadIdx.x) >> 6;
    int lane = threadIdx.x & 63;
    if (wid >= n) return;
    float4 v = h[wid * 64 + lane];
    float s = red32(v.x * v.x + v.y * v.y + v.z * v.z + v.w * v.w);
    float tot = rl_f(s, 31) + rl_f(s, 63);
    float rs = rsqrtf(tot + 1e-16f);
    H2U u0, u1;
    u0.h = __floats2half2_rn(v.x * rs, v.y * rs);
    u1.h = __floats2half2_rn(v.z * rs, v.w * rs);
    hn[wid * 64 + lane] = make_uint2(u0.u, u1.u);   // normalized fp16 row
    if (lane == 0) nrm[wid] = 1.0f / rs;            // ||h||
}

// ---------------- fused layer ------------------------------------------------
// One wave per dst node. fp16 NORMALIZED mirror rows: 512 B = 32 lanes x 16 B,
// so ONE dwordx4 wave-load fetches TWO edge rows (lanes 0-31 -> edge A,
// lanes 32-63 -> edge B). Tail edges are folded into the last 4-edge group via
// clamped indices + validity-zeroed weights (dummy slots hit the chunk's
// edge-0 row, which is already cache-warm).

__global__ __launch_bounds__(256, 6)
void fused_kernel(const uint4* __restrict__ hnin, const float* __restrict__ nrmin,
                  const int* __restrict__ rowptr, const int* __restrict__ esrc,
                  const float* __restrict__ betas, int layer,
                  float4* __restrict__ outf, uint4* __restrict__ hnout,
                  float* __restrict__ nrmout, int lastLayer, int n) {
    int wid  = (blockIdx.x * blockDim.x + threadIdx.x) >> 6;
    int lane = threadIdx.x & 63;
    if (wid >= n) return;
    int q = lane & 31;
    bool hiHalf = lane >= 32;

    float a[8];
    unpack8(hnin[wid * 32 + q], a);      // dst row (normalized), both halves same
    float beta = betas[layer];

    int beg = rowptr[wid], end = rowptr[wid + 1];
    float acc[8] = {0, 0, 0, 0, 0, 0, 0, 0};
    float dsum = 0.f;

    for (int base = beg; base < end; base += 64) {
        int idx = base + lane;
        int s_l = 0; float nm_l = 0.f;
        if (idx < end) { s_l = esrc[idx]; nm_l = nrmin[s_l]; }
        int m = end - base; if (m > 64) m = 64;

        uint4 b0, b1;
        {   // prologue: group 0 (indices clamped to 0 when beyond m)
            int tB = 1 < m ? 1 : 0, tC = 2 < m ? 2 : 0, tD = 3 < m ? 3 : 0;
            int sA = __builtin_amdgcn_readlane(s_l, 0);
            int sB = __builtin_amdgcn_readlane(s_l, tB);
            int sC = __builtin_amdgcn_readlane(s_l, tC);
            int sD = __builtin_amdgcn_readlane(s_l, tD);
            b0 = hnin[(hiHalf ? sB : sA) * 32 + q];
            b1 = hnin[(hiHalf ? sD : sC) * 32 + q];
        }
        for (int g = 0; g < m; g += 4) {
            float v0[8], v1[8];
            unpack8(b0, v0);
            unpack8(b1, v1);
            bool vB = g + 1 < m, vC = g + 2 < m, vD = g + 3 < m;
            float nmA = rl_f(nm_l, g);
            float nmB = rl_f(nm_l, vB ? g + 1 : 0);
            float nmC = rl_f(nm_l, vC ? g + 2 : 0);
            float nmD = rl_f(nm_l, vD ? g + 3 : 0);
            int gn = g + 4;
            if (gn < m) {                // prefetch next group (clamped)
                int tB = gn + 1 < m ? gn + 1 : 0;
                int tC = gn + 2 < m ? gn + 2 : 0;
                int tD = gn + 3 < m ? gn + 3 : 0;
                int sA = __builtin_amdgcn_readlane(s_l, gn);
                int sB = __builtin_amdgcn_readlane(s_l, tB);
                int sC = __builtin_amdgcn_readlane(s_l, tC);
                int sD = __builtin_amdgcn_readlane(s_l, tD);
                b0 = hnin[(hiHalf ? sB : sA) * 32 + q];
                b1 = hnin[(hiHalf ? sD : sC) * 32 + q];
            }
            float p0 = 0.f, p1 = 0.f;
            #pragma unroll
            for (int j = 0; j < 8; ++j) { p0 += a[j] * v0[j]; p1 += a[j] * v1[j]; }
            p0 = red32(p0); p1 = red32(p1);
            float xA = __expf(beta * rl_f(p0, 31));
            float xB = vB ? __expf(beta * rl_f(p0, 63)) : 0.f;
            float xC = vC ? __expf(beta * rl_f(p1, 31)) : 0.f;
            float xD = vD ? __expf(beta * rl_f(p1, 63)) : 0.f;
            dsum += (xA + xB) + (xC + xD);            // uniform on all lanes
            float e0 = hiHalf ? xB * nmB : xA * nmA;  // this lane's v0-edge weight
            float e1 = hiHalf ? xD * nmD : xC * nmC;  // this lane's v1-edge weight
            #pragma unroll
            for (int j = 0; j < 8; ++j) acc[j] += e0 * v0[j] + e1 * v1[j];
        }
    }

    // combine the two half-accumulators (symmetric: all lanes get the sum)
    #pragma unroll
    for (int j = 0; j < 8; ++j) acc[j] += __shfl_xor(acc[j], 32);

    float r = 1.f / (dsum + 1e-16f);
    float w[8];
    float ss = 0.f;
    #pragma unroll
    for (int j = 0; j < 8; ++j) {
        w[j] = fmaxf(acc[j] * r, 0.f);
        ss += w[j] * w[j];
    }
    ss = red32(ss);
    float ssum = rl_f(ss, 31);
    float rs = rsqrtf(ssum + 1e-16f);

    if (!hiHalf) {
        if (lastLayer) {
            outf[wid * 64 + q * 2]     = make_float4(w[0], w[1], w[2], w[3]);
            outf[wid * 64 + q * 2 + 1] = make_float4(w[4], w[5], w[6], w[7]);
        } else {
            H2U u0, u1, u2, u3;
            u0.h = __floats2half2_rn(w[0] * rs, w[1] * rs);
            u1.h = __floats2half2_rn(w[2] * rs, w[3] * rs);
            u2.h = __floats2half2_rn(w[4] * rs, w[5] * rs);
            u3.h = __floats2half2_rn(w[6] * rs, w[7] * rs);
            hnout[wid * 32 + q] = make_uint4(u0.u, u1.u, u2.u, u3.u);
            if (lane == 0) nrmout[wid] = 1.0f / rs;
        }
    }
}

// ---------------- launch -----------------------------------------------------

extern "C" void kernel_launch(void* const* d_in, const int* in_sizes, int n_in,
                              void* d_out, int out_size, void* d_ws, size_t ws_size,
                              hipStream_t stream) {
    const float* feats = (const float*)d_in[0];
    const int*   src   = (const int*)d_in[1];
    const int*   dst   = (const int*)d_in[2];
    const float* betas = (const float*)d_in[3];
    float* out = (float*)d_out;

    uint4* hn0       = (uint4*)d_ws;                   // NN*32 uint4 (5.12 MB)
    uint4* hn1       = hn0 + NN * 32;                  // NN*32 uint4 (5.12 MB)
    float* nrm0      = (float*)(hn1 + NN * 32);        // NN floats
    float* nrm1      = nrm0 + NN;                      // NN floats
    int*   rowptr    = (int*)(nrm1 + NN);              // NN+1 ints
    int*   cnt       = rowptr + (NN + 1);              // NN ints
    int*   esrc      = cnt + NN;                       // NE ints
    int*   rank      = esrc + NE;                      // NE ints
    int*   blockhist = rank + NE;                      // BH*NN ints (2.56 MB)

    // CSR build — no global atomics, no memsets
    hist_rank_kernel<<<BH, 256, 0, stream>>>(dst, blockhist, rank);
    colscan_kernel<<<(NN + 255) / 256, 256, 0, stream>>>(blockhist, cnt, NN);
    scan_kernel<<<1, 256, 0, stream>>>(cnt, rowptr, NN);
    scatter2_kernel<<<(NE + 255) / 256, 256, 0, stream>>>(src, dst, rank, blockhist,
                                                          rowptr, esrc, NE);

    // layer-0: normalized fp16 mirror + norms
    norm_kernel<<<(NN * 64 + 255) / 256, 256, 0, stream>>>((const float4*)feats,
                                                           (uint2*)hn0, nrm0, NN);

    const int node_blocks = (NN + 3) / 4;   // one wave per node, 4 waves/block

    const uint4* hnin = hn0;
    const float* nrmin = nrm0;
    for (int l = 0; l < 4; ++l) {
        uint4* hnout  = (l & 1) ? hn0 : hn1;
        float* nrmout = (l & 1) ? nrm0 : nrm1;
        fused_kernel<<<node_blocks, 256, 0, stream>>>(hnin, nrmin, rowptr, esrc,
                                                      betas, l, (float4*)out,
                                                      hnout, nrmout,
                                                      (l == 3) ? 1 : 0, NN);
        hnin = hnout;
        nrmin = nrmout;
    }
}

// Round 12
// 156.849 us; speedup vs baseline: 1.2836x; 1.0637x over previous
//
#include <hip/hip_runtime.h>
#include <hip/hip_fp16.h>

#define NN 10000
#define NE 320000
#define D 256
#define BH 128         // histogram blocks
#define EPB (NE / BH)  // 2500 edges per block (exact)

// ---------------- DPP cross-lane helpers (VALU pipe) -------------------------

template<int CTRL>
__device__ __forceinline__ float dpp_add(float x) {
    int y = __builtin_amdgcn_update_dpp(0, __float_as_int(x), CTRL, 0xF, 0xF, true);
    return x + __int_as_float(y);
}

// 32-lane reduce: after this, lane31 = sum(lanes 0..31), lane63 = sum(lanes 32..63)
__device__ __forceinline__ float red32(float x) {
    x = dpp_add<0x111>(x);   // row_shr:1
    x = dpp_add<0x112>(x);   // row_shr:2
    x = dpp_add<0x114>(x);   // row_shr:4
    x = dpp_add<0x118>(x);   // row_shr:8
    x = dpp_add<0x142>(x);   // row_bcast15
    return x;
}

__device__ __forceinline__ float rl_f(float x, int t) {
    return __int_as_float(__builtin_amdgcn_readlane(__float_as_int(x), t));
}

union H2U { __half2 h; unsigned u; };

__device__ __forceinline__ void unpack8(uint4 r, float* v) {
    H2U a, b, c, d; a.u = r.x; b.u = r.y; c.u = r.z; d.u = r.w;
    float2 f;
    f = __half22float2(a.h); v[0] = f.x; v[1] = f.y;
    f = __half22float2(b.h); v[2] = f.x; v[3] = f.y;
    f = __half22float2(c.h); v[4] = f.x; v[5] = f.y;
    f = __half22float2(d.h); v[6] = f.x; v[7] = f.y;
}

// ---------------- CSR build: atomic-free (LDS histograms) --------------------

__global__ void hist_rank_kernel(const int* __restrict__ dst,
                                 int* __restrict__ blockhist, int* __restrict__ rank) {
    __shared__ int lh[NN];                       // 40 KB
    for (int i = threadIdx.x; i < NN; i += 256) lh[i] = 0;
    __syncthreads();
    int e0 = blockIdx.x * EPB, e1 = e0 + EPB;
    for (int e = e0 + threadIdx.x; e < e1; e += 256)
        rank[e] = atomicAdd(&lh[dst[e]], 1);     // LDS atomic
    __syncthreads();
    int* bh = blockhist + blockIdx.x * NN;
    for (int i = threadIdx.x; i < NN; i += 256) bh[i] = lh[i];
}

__global__ void colscan_kernel(int* __restrict__ blockhist, int* __restrict__ cnt, int n) {
    int d = blockIdx.x * blockDim.x + threadIdx.x;
    if (d >= n) return;
    int run = 0;
    for (int b = 0; b < BH; ++b) {
        int v = blockhist[b * NN + d];           // coalesced across d
        blockhist[b * NN + d] = run;
        run += v;
    }
    cnt[d] = run;
}

__global__ void scan_kernel(const int* __restrict__ cnt, int* __restrict__ rowptr, int n) {
    __shared__ int part[256];
    int t = threadIdx.x;
    int chunk = (n + 255) / 256;
    int b = t * chunk;
    int e = b + chunk; if (e > n) e = n;
    int s = 0;
    for (int i = b; i < e; ++i) s += cnt[i];
    part[t] = s;
    __syncthreads();
    for (int off = 1; off < 256; off <<= 1) {
        int v = (t >= off) ? part[t - off] : 0;
        __syncthreads();
        part[t] += v;
        __syncthreads();
    }
    int acc = part[t] - s;
    for (int i = b; i < e; ++i) { rowptr[i] = acc; acc += cnt[i]; }
    if (e == n && b < n) rowptr[n] = acc;
}

__global__ void scatter2_kernel(const int* __restrict__ src, const int* __restrict__ dst,
                                const int* __restrict__ rank, const int* __restrict__ blockhist,
                                const int* __restrict__ rowptr, int* __restrict__ esrc, int nE) {
    int e = blockIdx.x * blockDim.x + threadIdx.x;
    if (e >= nE) return;
    int b = e / EPB;
    int d = dst[e];
    esrc[rowptr[d] + blockhist[b * NN + d] + rank[e]] = src[e];
}

// ---------------- layer-0: normalized fp16 mirror + norms --------------------

__global__ void norm_kernel(const float4* __restrict__ h, uint2* __restrict__ hn,
                            float* __restrict__ nrm, int n) {
    int wid  = (blockIdx.x * blockDim.x + threadIdx.x) >> 6;
    int lane = threadIdx.x & 63;
    if (wid >= n) return;
    float4 v = h[wid * 64 + lane];
    float s = red32(v.x * v.x + v.y * v.y + v.z * v.z + v.w * v.w);
    float tot = rl_f(s, 31) + rl_f(s, 63);
    float rs = rsqrtf(tot + 1e-16f);
    H2U u0, u1;
    u0.h = __floats2half2_rn(v.x * rs, v.y * rs);
    u1.h = __floats2half2_rn(v.z * rs, v.w * rs);
    hn[wid * 64 + lane] = make_uint2(u0.u, u1.u);   // normalized fp16 row
    if (lane == 0) nrm[wid] = 1.0f / rs;            // ||h||
}

// ---------------- fused layer ------------------------------------------------
// PERSISTENT grid-stride: exactly 6 blocks/CU co-resident for the whole
// kernel; each wave handles ~6.5 nodes. Inner loop identical to round 9:
// fp16 normalized mirror rows (512 B = 32 lanes x 16 B), one dwordx4
// wave-load fetches TWO edge rows; dot = cos directly; weight = ex*||h_src||.

__global__ __launch_bounds__(256, 6)
void fused_kernel(const uint4* __restrict__ hnin, const float* __restrict__ nrmin,
                  const int* __restrict__ rowptr, const int* __restrict__ esrc,
                  const float* __restrict__ betas, int layer,
                  float4* __restrict__ outf, uint4* __restrict__ hnout,
                  float* __restrict__ nrmout, int lastLayer, int n) {
    int lane = threadIdx.x & 63;
    int wv0  = (blockIdx.x * blockDim.x + threadIdx.x) >> 6;
    int nwv  = (gridDim.x * blockDim.x) >> 6;
    int q = lane & 31;
    bool hiHalf = lane >= 32;
    float beta = betas[layer];

    for (int wid = wv0; wid < n; wid += nwv) {
        float a[8];
        unpack8(hnin[wid * 32 + q], a);      // dst row (normalized), both halves same

        int beg = rowptr[wid], end = rowptr[wid + 1];
        float acc[8] = {0, 0, 0, 0, 0, 0, 0, 0};
        float dsum = 0.f;

        for (int base = beg; base < end; base += 64) {
            int idx = base + lane;
            int s_l = 0; float nm_l = 0.f;
            if (idx < end) { s_l = esrc[idx]; nm_l = nrmin[s_l]; }
            int m = end - base; if (m > 64) m = 64;

            int nf = m & ~3;                 // full groups of 4 edges (2 loads)
            uint4 b0, b1;
            if (nf > 0) {
                int sA = __builtin_amdgcn_readlane(s_l, 0);
                int sB = __builtin_amdgcn_readlane(s_l, 1);
                int sC = __builtin_amdgcn_readlane(s_l, 2);
                int sD = __builtin_amdgcn_readlane(s_l, 3);
                b0 = hnin[(hiHalf ? sB : sA) * 32 + q];
                b1 = hnin[(hiHalf ? sD : sC) * 32 + q];
            }
            for (int g = 0; g < nf; g += 4) {
                float v0[8], v1[8];
                unpack8(b0, v0);
                unpack8(b1, v1);
                float nmA = rl_f(nm_l, g),     nmB = rl_f(nm_l, g + 1);
                float nmC = rl_f(nm_l, g + 2), nmD = rl_f(nm_l, g + 3);
                int gn = g + 4;
                if (gn < nf) {               // issue next 2 two-row gathers early
                    int sA = __builtin_amdgcn_readlane(s_l, gn);
                    int sB = __builtin_amdgcn_readlane(s_l, gn + 1);
                    int sC = __builtin_amdgcn_readlane(s_l, gn + 2);
                    int sD = __builtin_amdgcn_readlane(s_l, gn + 3);
                    b0 = hnin[(hiHalf ? sB : sA) * 32 + q];
                    b1 = hnin[(hiHalf ? sD : sC) * 32 + q];
                }
                float p0 = 0.f, p1 = 0.f;
                #pragma unroll
                for (int j = 0; j < 8; ++j) { p0 += a[j] * v0[j]; p1 += a[j] * v1[j]; }
                p0 = red32(p0); p1 = red32(p1);
                float xA = __expf(beta * rl_f(p0, 31));
                float xB = __expf(beta * rl_f(p0, 63));
                float xC = __expf(beta * rl_f(p1, 31));
                float xD = __expf(beta * rl_f(p1, 63));
                dsum += (xA + xB) + (xC + xD);            // uniform on all lanes
                float e0 = hiHalf ? xB * nmB : xA * nmA;  // this lane's v0-edge weight
                float e1 = hiHalf ? xD * nmD : xC * nmC;  // this lane's v1-edge weight
                #pragma unroll
                for (int j = 0; j < 8; ++j) acc[j] += e0 * v0[j] + e1 * v1[j];
            }
            for (int t = nf; t < m; ++t) {   // remainder: one edge, both halves same row
                int   sA  = __builtin_amdgcn_readlane(s_l, t);
                float nmA = rl_f(nm_l, t);
                float v0[8]; unpack8(hnin[sA * 32 + q], v0);
                float p0 = 0.f;
                #pragma unroll
                for (int j = 0; j < 8; ++j) p0 += a[j] * v0[j];
                p0 = red32(p0);
                float xA = __expf(beta * rl_f(p0, 31));
                dsum += xA;
                float e0 = hiHalf ? 0.f : xA * nmA;       // count once (low half only)
                #pragma unroll
                for (int j = 0; j < 8; ++j) acc[j] += e0 * v0[j];
            }
        }

        // combine the two half-accumulators (symmetric: all lanes get the sum)
        #pragma unroll
        for (int j = 0; j < 8; ++j) acc[j] += __shfl_xor(acc[j], 32);

        float r = 1.f / (dsum + 1e-16f);
        float w[8];
        float ss = 0.f;
        #pragma unroll
        for (int j = 0; j < 8; ++j) {
            w[j] = fmaxf(acc[j] * r, 0.f);
            ss += w[j] * w[j];
        }
        ss = red32(ss);
        float ssum = rl_f(ss, 31);
        float rs = rsqrtf(ssum + 1e-16f);

        if (!hiHalf) {
            if (lastLayer) {
                outf[wid * 64 + q * 2]     = make_float4(w[0], w[1], w[2], w[3]);
                outf[wid * 64 + q * 2 + 1] = make_float4(w[4], w[5], w[6], w[7]);
            } else {
                H2U u0, u1, u2, u3;
                u0.h = __floats2half2_rn(w[0] * rs, w[1] * rs);
                u1.h = __floats2half2_rn(w[2] * rs, w[3] * rs);
                u2.h = __floats2half2_rn(w[4] * rs, w[5] * rs);
                u3.h = __floats2half2_rn(w[6] * rs, w[7] * rs);
                hnout[wid * 32 + q] = make_uint4(u0.u, u1.u, u2.u, u3.u);
                if (lane == 0) nrmout[wid] = 1.0f / rs;
            }
        }
    }
}

// ---------------- launch -----------------------------------------------------

extern "C" void kernel_launch(void* const* d_in, const int* in_sizes, int n_in,
                              void* d_out, int out_size, void* d_ws, size_t ws_size,
                              hipStream_t stream) {
    const float* feats = (const float*)d_in[0];
    const int*   src   = (const int*)d_in[1];
    const int*   dst   = (const int*)d_in[2];
    const float* betas = (const float*)d_in[3];
    float* out = (float*)d_out;

    uint4* hn0       = (uint4*)d_ws;                   // NN*32 uint4 (5.12 MB)
    uint4* hn1       = hn0 + NN * 32;                  // NN*32 uint4 (5.12 MB)
    float* nrm0      = (float*)(hn1 + NN * 32);        // NN floats
    float* nrm1      = nrm0 + NN;                      // NN floats
    int*   rowptr    = (int*)(nrm1 + NN);              // NN+1 ints
    int*   cnt       = rowptr + (NN + 1);              // NN ints
    int*   esrc      = cnt + NN;                       // NE ints
    int*   rank      = esrc + NE;                      // NE ints
    int*   blockhist = rank + NE;                      // BH*NN ints (5.12 MB)

    // CSR build — no global atomics, no memsets
    hist_rank_kernel<<<BH, 256, 0, stream>>>(dst, blockhist, rank);
    colscan_kernel<<<(NN + 255) / 256, 256, 0, stream>>>(blockhist, cnt, NN);
    scan_kernel<<<1, 256, 0, stream>>>(cnt, rowptr, NN);
    scatter2_kernel<<<(NE + 255) / 256, 256, 0, stream>>>(src, dst, rank, blockhist,
                                                          rowptr, esrc, NE);

    // layer-0: normalized fp16 mirror + norms
    norm_kernel<<<(NN * 64 + 255) / 256, 256, 0, stream>>>((const float4*)feats,
                                                           (uint2*)hn0, nrm0, NN);

    const int fused_blocks = 1536;   // 6 blocks/CU x 256 CUs: fully co-resident

    const uint4* hnin = hn0;
    const float* nrmin = nrm0;
    for (int l = 0; l < 4; ++l) {
        uint4* hnout  = (l & 1) ? hn0 : hn1;
        float* nrmout = (l & 1) ? nrm0 : nrm1;
        fused_kernel<<<fused_blocks, 256, 0, stream>>>(hnin, nrmin, rowptr, esrc,
                                                       betas, l, (float4*)out,
                                                       hnout, nrmout,
                                                       (l == 3) ? 1 : 0, NN);
        hnin = hnout;
        nrmin = nrmout;
    }
}

// Round 15
// 156.821 us; speedup vs baseline: 1.2838x; 1.0002x over previous
//
#include <hip/hip_runtime.h>
#include <hip/hip_fp16.h>

#define NN 10000
#define NE 320000
#define D 256
#define BH 128         // histogram blocks
#define EPB (NE / BH)  // 2500 edges per block (exact)

// ---------------- DPP cross-lane helpers (VALU pipe) -------------------------

template<int CTRL>
__device__ __forceinline__ float dpp_add(float x) {
    int y = __builtin_amdgcn_update_dpp(0, __float_as_int(x), CTRL, 0xF, 0xF, true);
    return x + __int_as_float(y);
}

// 32-lane reduce: after this, lane31 = sum(lanes 0..31), lane63 = sum(lanes 32..63)
__device__ __forceinline__ float red32(float x) {
    x = dpp_add<0x111>(x);   // row_shr:1
    x = dpp_add<0x112>(x);   // row_shr:2
    x = dpp_add<0x114>(x);   // row_shr:4
    x = dpp_add<0x118>(x);   // row_shr:8
    x = dpp_add<0x142>(x);   // row_bcast15
    return x;
}

__device__ __forceinline__ float rl_f(float x, int t) {
    return __int_as_float(__builtin_amdgcn_readlane(__float_as_int(x), t));
}

union H2U { __half2 h; unsigned u; };

__device__ __forceinline__ void unpack8(uint4 r, float* v) {
    H2U a, b, c, d; a.u = r.x; b.u = r.y; c.u = r.z; d.u = r.w;
    float2 f;
    f = __half22float2(a.h); v[0] = f.x; v[1] = f.y;
    f = __half22float2(b.h); v[2] = f.x; v[3] = f.y;
    f = __half22float2(c.h); v[4] = f.x; v[5] = f.y;
    f = __half22float2(d.h); v[6] = f.x; v[7] = f.y;
}

// ---------------- CSR build: atomic-free (LDS histograms) --------------------

__global__ void hist_rank_kernel(const int* __restrict__ dst,
                                 int* __restrict__ blockhist, int* __restrict__ rank) {
    __shared__ int lh[NN];                       // 40 KB
    for (int i = threadIdx.x; i < NN; i += 256) lh[i] = 0;
    __syncthreads();
    int e0 = blockIdx.x * EPB, e1 = e0 + EPB;
    for (int e = e0 + threadIdx.x; e < e1; e += 256)
        rank[e] = atomicAdd(&lh[dst[e]], 1);     // LDS atomic
    __syncthreads();
    int* bh = blockhist + blockIdx.x * NN;
    for (int i = threadIdx.x; i < NN; i += 256) bh[i] = lh[i];
}

__global__ void colscan_kernel(int* __restrict__ blockhist, int* __restrict__ cnt, int n) {
    int d = blockIdx.x * blockDim.x + threadIdx.x;
    if (d >= n) return;
    int run = 0;
    for (int b = 0; b < BH; ++b) {
        int v = blockhist[b * NN + d];           // coalesced across d
        blockhist[b * NN + d] = run;
        run += v;
    }
    cnt[d] = run;
}

__global__ void scan_kernel(const int* __restrict__ cnt, int* __restrict__ rowptr, int n) {
    __shared__ int part[256];
    int t = threadIdx.x;
    int chunk = (n + 255) / 256;
    int b = t * chunk;
    int e = b + chunk; if (e > n) e = n;
    int s = 0;
    for (int i = b; i < e; ++i) s += cnt[i];
    part[t] = s;
    __syncthreads();
    for (int off = 1; off < 256; off <<= 1) {
        int v = (t >= off) ? part[t - off] : 0;
        __syncthreads();
        part[t] += v;
        __syncthreads();
    }
    int acc = part[t] - s;
    for (int i = b; i < e; ++i) { rowptr[i] = acc; acc += cnt[i]; }
    if (e == n && b < n) rowptr[n] = acc;
}

__global__ void scatter2_kernel(const int* __restrict__ src, const int* __restrict__ dst,
                                const int* __restrict__ rank, const int* __restrict__ blockhist,
                                const int* __restrict__ rowptr, int* __restrict__ esrc, int nE) {
    int e = blockIdx.x * blockDim.x + threadIdx.x;
    if (e >= nE) return;
    int b = e / EPB;
    int d = dst[e];
    esrc[rowptr[d] + blockhist[b * NN + d] + rank[e]] = src[e];
}

// ---------------- layer-0: normalized fp16 mirror + norms --------------------

__global__ void norm_kernel(const float4* __restrict__ h, uint2* __restrict__ hn,
                            float* __restrict__ nrm, int n) {
    int wid  = (blockIdx.x * blockDim.x + threadIdx.x) >> 6;
    int lane = threadIdx.x & 63;
    if (wid >= n) return;
    float4 v = h[wid * 64 + lane];
    float s = red32(v.x * v.x + v.y * v.y + v.z * v.z + v.w * v.w);
    float tot = rl_f(s, 31) + rl_f(s, 63);
    float rs = rsqrtf(tot + 1e-16f);
    H2U u0, u1;
    u0.h = __floats2half2_rn(v.x * rs, v.y * rs);
    u1.h = __floats2half2_rn(v.z * rs, v.w * rs);
    hn[wid * 64 + lane] = make_uint2(u0.u, u1.u);   // normalized fp16 row
    if (lane == 0) nrm[wid] = 1.0f / rs;            // ||h||
}

// ---------------- fused layer ------------------------------------------------
// PERSISTENT grid-stride: 6 blocks/CU co-resident. fp16 normalized mirror rows
// (512 B = 32 lanes x 16 B): one dwordx4 wave-load fetches TWO edge rows;
// dot = cos directly; aggregation weight = ex * ||h_src||.

__global__ __launch_bounds__(256, 6)
void fused_kernel(const uint4* __restrict__ hnin, const float* __restrict__ nrmin,
                  const int* __restrict__ rowptr, const int* __restrict__ esrc,
                  const float* __restrict__ betas, int layer,
                  float4* __restrict__ outf, uint4* __restrict__ hnout,
                  float* __restrict__ nrmout, int lastLayer, int n) {
    int lane = threadIdx.x & 63;
    int wv0  = (blockIdx.x * blockDim.x + threadIdx.x) >> 6;
    int nwv  = (gridDim.x * blockDim.x) >> 6;
    int q = lane & 31;
    bool hiHalf = lane >= 32;
    float beta = betas[layer];

    for (int wid = wv0; wid < n; wid += nwv) {
        float a[8];
        unpack8(hnin[wid * 32 + q], a);      // dst row (normalized), both halves same

        int beg = rowptr[wid], end = rowptr[wid + 1];
        float acc[8] = {0, 0, 0, 0, 0, 0, 0, 0};
        float dsum = 0.f;

        for (int base = beg; base < end; base += 64) {
            int idx = base + lane;
            int s_l = 0; float nm_l = 0.f;
            if (idx < end) { s_l = esrc[idx]; nm_l = nrmin[s_l]; }
            int m = end - base; if (m > 64) m = 64;

            int nf = m & ~3;                 // full groups of 4 edges (2 loads)
            uint4 b0, b1;
            if (nf > 0) {
                int sA = __builtin_amdgcn_readlane(s_l, 0);
                int sB = __builtin_amdgcn_readlane(s_l, 1);
                int sC = __builtin_amdgcn_readlane(s_l, 2);
                int sD = __builtin_amdgcn_readlane(s_l, 3);
                b0 = hnin[(hiHalf ? sB : sA) * 32 + q];
                b1 = hnin[(hiHalf ? sD : sC) * 32 + q];
            }
            for (int g = 0; g < nf; g += 4) {
                float v0[8], v1[8];
                unpack8(b0, v0);
                unpack8(b1, v1);
                float nmA = rl_f(nm_l, g),     nmB = rl_f(nm_l, g + 1);
                float nmC = rl_f(nm_l, g + 2), nmD = rl_f(nm_l, g + 3);
                int gn = g + 4;
                if (gn < nf) {               // issue next 2 two-row gathers early
                    int sA = __builtin_amdgcn_readlane(s_l, gn);
                    int sB = __builtin_amdgcn_readlane(s_l, gn + 1);
                    int sC = __builtin_amdgcn_readlane(s_l, gn + 2);
                    int sD = __builtin_amdgcn_readlane(s_l, gn + 3);
                    b0 = hnin[(hiHalf ? sB : sA) * 32 + q];
                    b1 = hnin[(hiHalf ? sD : sC) * 32 + q];
                }
                float p0 = 0.f, p1 = 0.f;
                #pragma unroll
                for (int j = 0; j < 8; ++j) { p0 += a[j] * v0[j]; p1 += a[j] * v1[j]; }
                p0 = red32(p0); p1 = red32(p1);
                float xA = __expf(beta * rl_f(p0, 31));
                float xB = __expf(beta * rl_f(p0, 63));
                float xC = __expf(beta * rl_f(p1, 31));
                float xD = __expf(beta * rl_f(p1, 63));
                dsum += (xA + xB) + (xC + xD);            // uniform on all lanes
                float e0 = hiHalf ? xB * nmB : xA * nmA;  // this lane's v0-edge weight
                float e1 = hiHalf ? xD * nmD : xC * nmC;  // this lane's v1-edge weight
                #pragma unroll
                for (int j = 0; j < 8; ++j) acc[j] += e0 * v0[j] + e1 * v1[j];
            }
            for (int t = nf; t < m; ++t) {   // remainder: one edge, both halves same row
                int   sA  = __builtin_amdgcn_readlane(s_l, t);
                float nmA = rl_f(nm_l, t);
                float v0[8]; unpack8(hnin[sA * 32 + q], v0);
                float p0 = 0.f;
                #pragma unroll
                for (int j = 0; j < 8; ++j) p0 += a[j] * v0[j];
                p0 = red32(p0);
                float xA = __expf(beta * rl_f(p0, 31));
                dsum += xA;
                float e0 = hiHalf ? 0.f : xA * nmA;       // count once (low half only)
                #pragma unroll
                for (int j = 0; j < 8; ++j) acc[j] += e0 * v0[j];
            }
        }

        // combine the two half-accumulators (symmetric: all lanes get the sum)
        #pragma unroll
        for (int j = 0; j < 8; ++j) acc[j] += __shfl_xor(acc[j], 32);

        float r = 1.f / (dsum + 1e-16f);
        float w[8];
        float ss = 0.f;
        #pragma unroll
        for (int j = 0; j < 8; ++j) {
            w[j] = fmaxf(acc[j] * r, 0.f);
            ss += w[j] * w[j];
        }
        ss = red32(ss);
        float ssum = rl_f(ss, 31);
        float rs = rsqrtf(ssum + 1e-16f);

        if (!hiHalf) {
            if (lastLayer) {
                outf[wid * 64 + q * 2]     = make_float4(w[0], w[1], w[2], w[3]);
                outf[wid * 64 + q * 2 + 1] = make_float4(w[4], w[5], w[6], w[7]);
            } else {
                H2U u0, u1, u2, u3;
                u0.h = __floats2half2_rn(w[0] * rs, w[1] * rs);
                u1.h = __floats2half2_rn(w[2] * rs, w[3] * rs);
                u2.h = __floats2half2_rn(w[4] * rs, w[5] * rs);
                u3.h = __floats2half2_rn(w[6] * rs, w[7] * rs);
                hnout[wid * 32 + q] = make_uint4(u0.u, u1.u, u2.u, u3.u);
                if (lane == 0) nrmout[wid] = 1.0f / rs;
            }
        }
    }
}

// ---------------- launch -----------------------------------------------------

extern "C" void kernel_launch(void* const* d_in, const int* in_sizes, int n_in,
                              void* d_out, int out_size, void* d_ws, size_t ws_size,
                              hipStream_t stream) {
    const float* feats = (const float*)d_in[0];
    const int*   src   = (const int*)d_in[1];
    const int*   dst   = (const int*)d_in[2];
    const float* betas = (const float*)d_in[3];
    float* out = (float*)d_out;

    uint4* hn0       = (uint4*)d_ws;                   // NN*32 uint4 (5.12 MB)
    uint4* hn1       = hn0 + NN * 32;                  // NN*32 uint4 (5.12 MB)
    float* nrm0      = (float*)(hn1 + NN * 32);        // NN floats
    float* nrm1      = nrm0 + NN;                      // NN floats
    int*   rowptr    = (int*)(nrm1 + NN);              // NN+1 ints
    int*   cnt       = rowptr + (NN + 1);              // NN ints
    int*   esrc      = cnt + NN;                       // NE ints
    int*   rank      = esrc + NE;                      // NE ints
    int*   blockhist = rank + NE;                      // BH*NN ints (5.12 MB)

    // CSR build — no global atomics, no memsets
    hist_rank_kernel<<<BH, 256, 0, stream>>>(dst, blockhist, rank);
    colscan_kernel<<<(NN + 255) / 256, 256, 0, stream>>>(blockhist, cnt, NN);
    scan_kernel<<<1, 256, 0, stream>>>(cnt, rowptr, NN);
    scatter2_kernel<<<(NE + 255) / 256, 256, 0, stream>>>(src, dst, rank, blockhist,
                                                          rowptr, esrc, NE);

    // layer-0: normalized fp16 mirror + norms
    norm_kernel<<<(NN * 64 + 255) / 256, 256, 0, stream>>>((const float4*)feats,
                                                           (uint2*)hn0, nrm0, NN);

    const int fused_blocks = 1536;   // 6 blocks/CU x 256 CUs: fully co-resident

    const uint4* hnin = hn0;
    const float* nrmin = nrm0;
    for (int l = 0; l < 4; ++l) {
        uint4* hnout  = (l & 1) ? hn0 : hn1;
        float* nrmout = (l & 1) ? nrm0 : nrm1;
        fused_kernel<<<fused_blocks, 256, 0, stream>>>(hnin, nrmin, rowptr, esrc,
                                                       betas, l, (float4*)out,
                                                       hnout, nrmout,
                                                       (l == 3) ? 1 : 0, NN);
        hnin = hnout;
        nrmin = nrmout;
    }
}